// Round 5
// baseline (82.143 us; speedup 1.0000x reference)
//
#include <hip/hip_runtime.h>
#include <math.h>

// Problem constants (fixed by reference setup_inputs)
#define NN 32768
#define LL 256      // K dimension (leaves)
#define CC 64       // output cols (classes)

typedef __attribute__((ext_vector_type(8))) _Float16 half8;  // MFMA A/B frag (4 VGPRs)
typedef __attribute__((ext_vector_type(4))) _Float16 half4;  // 8B LDS store
typedef __attribute__((ext_vector_type(4))) float f32x4;     // MFMA C/D frag + load vec

// global -> LDS direct copy, 16B per lane. LDS dest must be the WAVE-UNIFORM
// base (HW adds lane*16 itself); global src is per-lane.
#define GLOAD_LDS16(g, l)                                                   \
    __builtin_amdgcn_global_load_lds(                                       \
        (const __attribute__((address_space(1))) void*)(g),                 \
        (__attribute__((address_space(3))) void*)(l), 16, 0, 0)

// ---------------------------------------------------------------------------
// prep_kernel (verified R0/R3/R4): softmax(leaf_scores) rows -> fp16,
// scattered into MFMA B-fragment order in ws. 256 blocks x 64 threads.
//   B-frag region (s,t): lane (q,m) holds B[k=s*32+q*8+j][n=t*16+m], j=0..7
// ---------------------------------------------------------------------------
__global__ __launch_bounds__(64) void prep_kernel(
    const float* __restrict__ scores, _Float16* __restrict__ wsB) {
    const int l = blockIdx.x;    // leaf row
    const int k = threadIdx.x;   // class col
    float v = scores[(size_t)l * CC + k];
    float mx = v;
    #pragma unroll
    for (int off = 32; off > 0; off >>= 1) mx = fmaxf(mx, __shfl_xor(mx, off));
    float e = __expf(v - mx);
    float sum = e;
    #pragma unroll
    for (int off = 32; off > 0; off >>= 1) sum += __shfl_xor(sum, off);
    _Float16 h = (_Float16)__fdividef(e, sum);

    const int s = l >> 5;          // k-step
    const int w = l & 31;
    const int q = w >> 3;          // quad within frag
    const int j = w & 7;           // element within frag
    const int t = k >> 4;          // n-tile
    const int m = k & 15;          // n within tile
    wsB[((s * 4 + t) * 64 + q * 16 + m) * 8 + j] = h;
}

// ---------------------------------------------------------------------------
// Main kernel: out = log( fp16(mu) @ Q )  via fp16 MFMA.
//
// R4 post-mortem: 4 structurally different stacks all land at 78.3-79.7 us;
// fitting dur = fill(45) + chain gives chain ~= 33 us for ALL of them. Theory:
// the 256 MiB poison fill (== L3 capacity) leaves L3 ~100% dirty right before
// our kernel; every mu line fetched must first EVICT a dirty victim to HBM
// (write-before-read serialization -> effective read BW ~2 TB/s, matching
// 75 MB / 33 us). This cost is cache-state, invariant to kernel structure —
// which is exactly what R0/R2/R3/R4 showed. rocprof's serialized replay lets
// the drain finish in idle gaps, so profiled kernels look fast (< top-5
// cutoff) while the timed run pays the contention.
//
// ONE-VARIABLE CHANGE vs R4: non-temporal (no-allocate) loads for mu and
// non-temporal stores for out. nt reads skip the allocate-evict dance; nt
// writes stop out's 8.4 MB from forcing further evictions. mu/out have zero
// reuse, so the hint costs nothing. B path (ws) stays cached — ws lines ARE
// the freshly-written dirty data, i.e. hot for us.
//
// Everything else byte-identical to R4 (harness-verified, absmax 3.9e-3):
//   A-LDS: byte addr = (row*512 + col*2) ^ ((row&7)<<4), same involution on
//   write (half4 per lane) and fragment read (ds_read_b128).
//   B: ws -> LDS via global_load_lds (fragment order is linear = HW pattern).
// ---------------------------------------------------------------------------
__global__ __launch_bounds__(256, 2) void leaf_mix_mfma_kernel(
    const float* __restrict__ mu, const float4* __restrict__ wsB,
    float* __restrict__ out) {
    __shared__ float Bs[8192];            // 32 KB fp16 B fragments (frag order)
    __shared__ _Float16 As[64 * 256];     // 32 KB fp16 A tile, XOR-swizzled

    const int tid  = threadIdx.x;
    const int wid  = tid >> 6;
    const int lane = tid & 63;
    const int quad = lane >> 4;
    const int m    = lane & 15;

    // ---- B: ws -> LDS direct, zero VGPRs, stays in flight all phase ----
    {
        const char* gsrc = (const char*)wsB;
        char* lbase = (char*)Bs;
        #pragma unroll
        for (int i = 0; i < 8; ++i) {
            const int blk16 = i * 256 + wid * 64;            // 16B units
            GLOAD_LDS16(gsrc + ((size_t)blk16 + lane) * 16,  // per-lane src
                        lbase + (size_t)blk16 * 16);         // uniform dest
        }
    }

    // ---- A: 16 coalesced float4 loads, NON-TEMPORAL (no L2/L3 allocate) ----
    // float4 idx = i*256 + tid  ->  row = i*4 + wid, cols [lane*4, lane*4+4)
    f32x4 areg[16];
    const f32x4* mublk = (const f32x4*)(mu + (size_t)blockIdx.x * 64 * LL);
    #pragma unroll
    for (int i = 0; i < 16; ++i)
        areg[i] = __builtin_nontemporal_load(&mublk[i * 256 + tid]);

    // ---- cvt A to fp16 + swizzled LDS write: 8B/lane, conflict-free ----
    {
        char* as = (char*)As;
        #pragma unroll
        for (int i = 0; i < 16; ++i) {
            const int row = i * 4 + wid;
            half4 h;
            h[0] = (_Float16)areg[i][0]; h[1] = (_Float16)areg[i][1];
            h[2] = (_Float16)areg[i][2]; h[3] = (_Float16)areg[i][3];
            *(half4*)(as + ((row * 512 + lane * 8) ^ ((row & 7) << 4))) = h;
        }
    }
    __syncthreads();   // compiler emits vmcnt(0): B's global_load_lds drained

    f32x4 acc[4] = {{0.f, 0.f, 0.f, 0.f}, {0.f, 0.f, 0.f, 0.f},
                    {0.f, 0.f, 0.f, 0.f}, {0.f, 0.f, 0.f, 0.f}};

    const char* asr = (const char*)As;
    const char* bsr = (const char*)Bs;
    const int arow   = wid * 16 + m;
    const int abase0 = arow * 512 + quad * 16;   // logical byte addr, +s*64/step
    const int axm    = (m & 7) << 4;             // swizzle mask (row&7 == m&7)
    #pragma unroll
    for (int s = 0; s < 8; ++s) {
        const half8 ah = *(const half8*)(asr + ((abase0 + s * 64) ^ axm));
        #pragma unroll
        for (int tt = 0; tt < 4; ++tt) {
            const half8 b = *(const half8*)(bsr + (s * 4 + tt) * 1024 + lane * 16);
            acc[tt] = __builtin_amdgcn_mfma_f32_16x16x32_f16(ah, b, acc[tt], 0, 0, 0);
        }
    }

    // ---- epilogue: C/D col = lane&15, row = quad*4 + reg; NT stores ----
    const size_t outRow0 = (size_t)blockIdx.x * 64 + wid * 16 + quad * 4;
    #pragma unroll
    for (int tt = 0; tt < 4; ++tt)
        #pragma unroll
        for (int r = 0; r < 4; ++r)
            __builtin_nontemporal_store(
                __logf(acc[tt][r]),
                &out[(outRow0 + r) * CC + tt * 16 + m]);
}

extern "C" void kernel_launch(void* const* d_in, const int* in_sizes, int n_in,
                              void* d_out, int out_size, void* d_ws, size_t ws_size,
                              hipStream_t stream) {
    const float* mu     = (const float*)d_in[0];   // (32768, 256) f32
    const float* scores = (const float*)d_in[1];   // (256, 64)    f32
    float* out = (float*)d_out;                    // (32768, 64)  f32

    prep_kernel<<<LL, CC, 0, stream>>>(scores, (_Float16*)d_ws);
    leaf_mix_mfma_kernel<<<NN / 64, 256, 0, stream>>>(mu, (const float4*)d_ws, out);
}

// Round 6
// 78.473 us; speedup vs baseline: 1.0468x; 1.0468x over previous
//
#include <hip/hip_runtime.h>
#include <math.h>

// Problem constants (fixed by reference setup_inputs)
#define NN 32768
#define LL 256      // K dimension (leaves)
#define CC 64       // output cols (classes)

typedef __attribute__((ext_vector_type(8))) _Float16 half8;  // MFMA A/B frag (4 VGPRs)
typedef __attribute__((ext_vector_type(4))) _Float16 half4;  // 8B LDS store
typedef __attribute__((ext_vector_type(4))) float f32x4;     // MFMA C/D frag + load vec

// global -> LDS direct copy, 16B per lane. LDS dest must be the WAVE-UNIFORM
// base (HW adds lane*16 itself); global src is per-lane.
#define GLOAD_LDS16(g, l)                                                   \
    __builtin_amdgcn_global_load_lds(                                       \
        (const __attribute__((address_space(1))) void*)(g),                 \
        (__attribute__((address_space(3))) void*)(l), 16, 0, 0)

// ---------------------------------------------------------------------------
// prep_kernel (verified R0/R3/R4): softmax(leaf_scores) rows -> fp16,
// scattered into MFMA B-fragment order in ws. 256 blocks x 64 threads.
//   B-frag region (s,t): lane (q,m) holds B[k=s*32+q*8+j][n=t*16+m], j=0..7
// ---------------------------------------------------------------------------
__global__ __launch_bounds__(64) void prep_kernel(
    const float* __restrict__ scores, _Float16* __restrict__ wsB) {
    const int l = blockIdx.x;    // leaf row
    const int k = threadIdx.x;   // class col
    float v = scores[(size_t)l * CC + k];
    float mx = v;
    #pragma unroll
    for (int off = 32; off > 0; off >>= 1) mx = fmaxf(mx, __shfl_xor(mx, off));
    float e = __expf(v - mx);
    float sum = e;
    #pragma unroll
    for (int off = 32; off > 0; off >>= 1) sum += __shfl_xor(sum, off);
    _Float16 h = (_Float16)__fdividef(e, sum);

    const int s = l >> 5;          // k-step
    const int w = l & 31;
    const int q = w >> 3;          // quad within frag
    const int j = w & 7;           // element within frag
    const int t = k >> 4;          // n-tile
    const int m = k & 15;          // n within tile
    wsB[((s * 4 + t) * 64 + q * 16 + m) * 8 + j] = h;
}

// ---------------------------------------------------------------------------
// Main kernel: out = log( fp16(mu) @ Q )  via fp16 MFMA.
//
// R5 post-mortem: nt hints HURT (82.1) -> mu/out like the cache; reverted.
// Calibrated decomposition (R1: fill 45 + fused 46 = 91) puts main at ~32 us
// in R0/R2/R3/R4 — INVARIANT under coalescing, VGPR caps, global_load_lds,
// cache hints. The untouched common factor: execution shape. 512 blocks on
// 256 CUs = 2 resident blocks/CU, launched once, all phase-locked: the whole
// chip issues loads at t=0, stalls at one vmcnt(0)+barrier, computes, exits.
// One-shot critical path, zero cross-tile overlap, no backfill.
//
// THIS ROUND'S CHANGE (one lever: grid/pipeline shape): 32-row tiles ->
// 1024 blocks. LDS = 16KB A + 32KB B = 48KB -> 3 resident blocks/CU
// (12 waves, was 8) + 256 backfill blocks that start as residents retire:
// phases stagger by occupancy AND block turnover, so one block's MFMA and
// epilogue overlap another's load-wait. Wave owns 16 rows x 32 cols
// (2x2 wave split of the tile), 16 MFMA; total MFMA count unchanged.
//
// Verified layouts carried over unchanged (absmax 3.9e-3, thr 2.16e-2):
//   A-LDS: byte = (row*512 + col*2) ^ ((row&7)<<4), same involution write/read
//   B: ws fragment order is linear -> global_load_lds direct
//   C/D: col = lane&15, row = quad*4 + reg
// ---------------------------------------------------------------------------
__global__ __launch_bounds__(256, 3) void leaf_mix_mfma_kernel(
    const float* __restrict__ mu, const float4* __restrict__ wsB,
    float* __restrict__ out) {
    __shared__ float Bs[8192];            // 32 KB fp16 B fragments (frag order)
    __shared__ _Float16 As[32 * 256];     // 16 KB fp16 A tile, XOR-swizzled

    const int tid  = threadIdx.x;
    const int wid  = tid >> 6;
    const int lane = tid & 63;
    const int quad = lane >> 4;
    const int m    = lane & 15;

    // ---- B: ws -> LDS direct, zero VGPRs, stays in flight all phase ----
    {
        const char* gsrc = (const char*)wsB;
        char* lbase = (char*)Bs;
        #pragma unroll
        for (int i = 0; i < 8; ++i) {
            const int blk16 = i * 256 + wid * 64;            // 16B units
            GLOAD_LDS16(gsrc + ((size_t)blk16 + lane) * 16,  // per-lane src
                        lbase + (size_t)blk16 * 16);         // uniform dest
        }
    }

    // ---- A: 8 coalesced float4 loads (32-row tile), all issued up front ----
    // float4 idx = i*256 + tid  ->  row = i*4 + wid, cols [lane*4, lane*4+4)
    f32x4 areg[8];
    const f32x4* mublk = (const f32x4*)(mu + (size_t)blockIdx.x * 32 * LL);
    #pragma unroll
    for (int i = 0; i < 8; ++i) areg[i] = mublk[i * 256 + tid];

    // ---- cvt A to fp16 + swizzled LDS write: 8B/lane, conflict-free ----
    {
        char* as = (char*)As;
        #pragma unroll
        for (int i = 0; i < 8; ++i) {
            const int row = i * 4 + wid;
            half4 h;
            h[0] = (_Float16)areg[i][0]; h[1] = (_Float16)areg[i][1];
            h[2] = (_Float16)areg[i][2]; h[3] = (_Float16)areg[i][3];
            *(half4*)(as + ((row * 512 + lane * 8) ^ ((row & 7) << 4))) = h;
        }
    }
    __syncthreads();   // compiler emits vmcnt(0): B's global_load_lds drained

    // ---- wave split: rows (wid>>1)*16, col half (wid&1)*32 ----
    f32x4 acc[2] = {{0.f, 0.f, 0.f, 0.f}, {0.f, 0.f, 0.f, 0.f}};

    const char* asr = (const char*)As;
    const char* bsr = (const char*)Bs;
    const int arow   = (wid >> 1) * 16 + m;      // (arow&7)==(m&7): 16|arow base
    const int abase0 = arow * 512 + quad * 16;   // logical byte addr, +s*64/step
    const int axm    = (m & 7) << 4;             // swizzle mask
    const int tbase  = (wid & 1) * 2;            // class tiles {tbase, tbase+1}
    #pragma unroll
    for (int s = 0; s < 8; ++s) {
        const half8 ah = *(const half8*)(asr + ((abase0 + s * 64) ^ axm));
        #pragma unroll
        for (int ttl = 0; ttl < 2; ++ttl) {
            const half8 b = *(const half8*)(
                bsr + (s * 4 + tbase + ttl) * 1024 + lane * 16);
            acc[ttl] = __builtin_amdgcn_mfma_f32_16x16x32_f16(ah, b, acc[ttl], 0, 0, 0);
        }
    }

    // ---- epilogue: C/D col = lane&15, row = quad*4 + reg ----
    const size_t outRow0 = (size_t)blockIdx.x * 32 + (wid >> 1) * 16 + quad * 4;
    #pragma unroll
    for (int ttl = 0; ttl < 2; ++ttl) {
        const int tt = tbase + ttl;
        #pragma unroll
        for (int r = 0; r < 4; ++r)
            out[(outRow0 + r) * CC + tt * 16 + m] = __logf(acc[ttl][r]);
    }
}

extern "C" void kernel_launch(void* const* d_in, const int* in_sizes, int n_in,
                              void* d_out, int out_size, void* d_ws, size_t ws_size,
                              hipStream_t stream) {
    const float* mu     = (const float*)d_in[0];   // (32768, 256) f32
    const float* scores = (const float*)d_in[1];   // (256, 64)    f32
    float* out = (float*)d_out;                    // (32768, 64)  f32

    prep_kernel<<<LL, CC, 0, stream>>>(scores, (_Float16*)d_ws);
    leaf_mix_mfma_kernel<<<NN / 32, 256, 0, stream>>>(mu, (const float4*)d_ws, out);
}